// Round 6
// baseline (160.353 us; speedup 1.0000x reference)
//
#include <hip/hip_runtime.h>

// Problem dims (fixed): B=4, T=2048, C=64, H=6, D=64, scale = 1/8.
// I/O dtype: float32 (bf16-rounded values). Internal Q/K/Vt/att are bf16.
// Round-6: same as round-5 (split-j attn, coalesced qkv stores, exp2-domain
// softmax) but __exp2f -> __builtin_amdgcn_exp2f (glibc math.h collision).

typedef unsigned short u16t;
typedef __attribute__((ext_vector_type(8))) short short8;   // 8 bf16 = 4 VGPRs (MFMA A/B frag)
typedef __attribute__((ext_vector_type(4))) float float4v;  // MFMA C/D frag

#define MFMA16(a, b, c) __builtin_amdgcn_mfma_f32_16x16x32_bf16((a), (b), (c), 0, 0, 0)

__device__ __forceinline__ float fexp2(float x) {  // v_exp_f32: D = 2^S0
  return __builtin_amdgcn_exp2f(x);
}
__device__ __forceinline__ float bf2f(u16t u) {
  return __uint_as_float(((unsigned)u) << 16);
}
__device__ __forceinline__ u16t f2bf(float f) {  // round-nearest-even
  unsigned u = __float_as_uint(f);
  u += 0x7fffu + ((u >> 16) & 1u);
  return (u16t)(u >> 16);
}
__device__ __forceinline__ u16t f2bf_trunc(float f) {  // truncate (hot path, P only)
  return (u16t)(__float_as_uint(f) >> 16);
}
__device__ __forceinline__ short8 load8_f32_bf16(const float* p) {
  float4 f0 = *(const float4*)p;
  float4 f1 = *(const float4*)(p + 4);
  short8 r;
  r[0] = (short)f2bf(f0.x); r[1] = (short)f2bf(f0.y);
  r[2] = (short)f2bf(f0.z); r[3] = (short)f2bf(f0.w);
  r[4] = (short)f2bf(f1.x); r[5] = (short)f2bf(f1.y);
  r[6] = (short)f2bf(f1.z); r[7] = (short)f2bf(f1.w);
  return r;
}

constexpr int Bb = 4, Tt = 2048, Cc = 64, Hh = 6, Dd = 64;
constexpr int BH = Bb * Hh;         // 24
constexpr int NQT = Tt / 64;        // 32 q-tiles of 64 rows
constexpr int LDT = 72;             // padded LDS row stride (144 B)
constexpr int JCT = 16;             // j-chunk in k-tiles (1024 j positions)
// exp2-domain: S' = S*log2(e); fold into Q pre-scale.
#define QSCALE (0.125f * 1.44269504088896f)
// Blocks per bh: qt>=16 -> 2 chunks (32 blocks), qt<16 -> 1 (16 blocks).
constexpr int RPB = 48;
constexpr int PSLOT = 4224;         // per-partial floats: 64*64 O + 64 m + 64 l

// ---------------------------------------------------------------------------
// Kernel 1: QKV projection via MFMA. Per block: one (b,h), 64 t-rows.
// Weights staged transposed in LDS (B-operand layout). Q/K/V all bounced
// through LDS for coalesced b128 global writes.
// ---------------------------------------------------------------------------
__global__ __launch_bounds__(256) void qkv_kernel(
    const float* __restrict__ x, const float* __restrict__ y,
    const float* __restrict__ Wq, const float* __restrict__ Wk,
    const float* __restrict__ Wv,
    u16t* __restrict__ Q, u16t* __restrict__ K, u16t* __restrict__ Vt) {
  __shared__ __align__(16) u16t wtq[64 * LDT];
  __shared__ __align__(16) u16t wtk[64 * LDT];
  __shared__ __align__(16) u16t wtv[64 * LDT];
  __shared__ __align__(16) u16t vl[64 * LDT];  // bounce buffer (reused 3x)

  int bid = blockIdx.x;
  int bh = bid >> 5, tt = bid & 31;
  int b = bh / Hh, h = bh - b * Hh;
  int tid = threadIdx.x;
  int w = tid >> 6, lane = tid & 63;
  int l15 = lane & 15, q4 = lane >> 4;

  {
    const float* wq = Wq + h * 4096;
    const float* wk = Wk + h * 4096;
    const float* wv = Wv + h * 4096;
#pragma unroll
    for (int i = 0; i < 16; ++i) {
      int idx = tid + i * 256;  // coalesced reads
      int c = idx >> 6, d = idx & 63;
      wtq[d * LDT + c] = f2bf(wq[idx]);
      wtk[d * LDT + c] = f2bf(wk[idx]);
      wtv[d * LDT + c] = f2bf(wv[idx]);
    }
  }

  int trow = tt * 64 + w * 16 + l15;
  const float* xrow = x + ((size_t)b * Tt + trow) * Cc;
  const float* yrow = y + ((size_t)b * Tt + trow) * Cc;
  short8 xa[2], ya[2];
#pragma unroll
  for (int kc = 0; kc < 2; ++kc) {
    xa[kc] = load8_f32_bf16(xrow + kc * 32 + q4 * 8);
    ya[kc] = load8_f32_bf16(yrow + kc * 32 + q4 * 8);
  }
  __syncthreads();

  float4v qa4[4], ka4[4], va4[4];
#pragma unroll
  for (int nc = 0; nc < 4; ++nc) {
    qa4[nc] = (float4v){0.f, 0.f, 0.f, 0.f};
    ka4[nc] = (float4v){0.f, 0.f, 0.f, 0.f};
    va4[nc] = (float4v){0.f, 0.f, 0.f, 0.f};
  }
#pragma unroll
  for (int nc = 0; nc < 4; ++nc) {
#pragma unroll
    for (int kc = 0; kc < 2; ++kc) {
      int off = (nc * 16 + l15) * LDT + kc * 32 + q4 * 8;
      short8 bq = *(const short8*)&wtq[off];
      short8 bk = *(const short8*)&wtk[off];
      short8 bv = *(const short8*)&wtv[off];
      qa4[nc] = MFMA16(xa[kc], bq, qa4[nc]);
      ka4[nc] = MFMA16(ya[kc], bk, ka4[nc]);
      va4[nc] = MFMA16(ya[kc], bv, va4[nc]);
    }
  }

  size_t tilebase = ((size_t)bh * Tt + tt * 64) * Dd;  // Q/K tile origin
  // --- Q (pre-scaled into exp2 domain) ---
#pragma unroll
  for (int reg = 0; reg < 4; ++reg)
#pragma unroll
    for (int nc = 0; nc < 4; ++nc)
      vl[(w * 16 + q4 * 4 + reg) * LDT + nc * 16 + l15] = f2bf(qa4[nc][reg] * QSCALE);
  __syncthreads();
#pragma unroll
  for (int i = 0; i < 2; ++i) {
    int id = tid * 2 + i;  // 0..511 chunks of 8 bf16
    int row = id >> 3, c8 = id & 7;
    *(uint4*)&Q[tilebase + row * 64 + c8 * 8] = *(const uint4*)&vl[row * LDT + c8 * 8];
  }
  __syncthreads();
  // --- K ---
#pragma unroll
  for (int reg = 0; reg < 4; ++reg)
#pragma unroll
    for (int nc = 0; nc < 4; ++nc)
      vl[(w * 16 + q4 * 4 + reg) * LDT + nc * 16 + l15] = f2bf(ka4[nc][reg]);
  __syncthreads();
#pragma unroll
  for (int i = 0; i < 2; ++i) {
    int id = tid * 2 + i;
    int row = id >> 3, c8 = id & 7;
    *(uint4*)&K[tilebase + row * 64 + c8 * 8] = *(const uint4*)&vl[row * LDT + c8 * 8];
  }
  __syncthreads();
  // --- V (transposed: Vt[bh, d, t]) ---
#pragma unroll
  for (int reg = 0; reg < 4; ++reg)
#pragma unroll
    for (int nc = 0; nc < 4; ++nc)
      vl[(nc * 16 + l15) * LDT + w * 16 + q4 * 4 + reg] = f2bf(va4[nc][reg]);
  __syncthreads();
#pragma unroll
  for (int i = 0; i < 2; ++i) {
    int id = tid * 2 + i;
    int d = id >> 3, c8 = id & 7;
    *(uint4*)&Vt[((size_t)bh * 64 + d) * Tt + tt * 64 + c8 * 8] =
        *(const uint4*)&vl[d * LDT + c8 * 8];
  }
}

// ---------------------------------------------------------------------------
// Kernel 2: causal flash attention with split-j. Block = (bh, qt, jc):
// qt>=16 is split into 2 j-chunks of <=16 k-tiles; chunk results go to pbuf
// as f32 partials (O, m, l); qt<16 writes att directly. Softmax in exp2
// domain (Q pre-scaled by scale*log2e).
// Grid: 24 * 48 = 1152 blocks, 256 thr (4 waves x 16 q-rows).
// ---------------------------------------------------------------------------
__global__ __launch_bounds__(256) void attn_kernel(
    const u16t* __restrict__ Q, const u16t* __restrict__ K,
    const u16t* __restrict__ Vt, u16t* __restrict__ att,
    float* __restrict__ pbuf) {
  __shared__ __align__(16) u16t Kl[64 * LDT];
  __shared__ __align__(16) u16t Vl[64 * LDT];
  __shared__ __align__(16) u16t Pl[4 * 16 * LDT];

  int bid = blockIdx.x;
  int bh = bid / RPB, r = bid - bh * RPB;
  int qt, jc;
  if (r < 32) { qt = 16 + (r >> 1); jc = r & 1; }
  else        { qt = 47 - r;        jc = 0;     }
  int b = bh / Hh, h = bh - (bh / Hh) * Hh;
  int tid = threadIdx.x;
  int w = tid >> 6;
  int lane = tid & 63;
  int l15 = lane & 15, q4 = lane >> 4;

  int j0 = (qt >= 16 && jc == 1) ? JCT : 0;
  int j1 = (qt >= 16 && jc == 0) ? JCT : qt + 1;

  const u16t* Qbase = Q + ((size_t)bh * Tt + qt * 64 + w * 16 + l15) * Dd;
  short8 qf0 = *(const short8*)(Qbase + q4 * 8);
  short8 qf1 = *(const short8*)(Qbase + 32 + q4 * 8);

  float4v O[4];
#pragma unroll
  for (int nc = 0; nc < 4; ++nc) O[nc] = (float4v){0.f, 0.f, 0.f, 0.f};
  float m_[4], l_[4];
#pragma unroll
  for (int i = 0; i < 4; ++i) { m_[i] = -1e30f; l_[i] = 0.f; }

  const u16t* Kbh = K + (size_t)bh * Tt * Dd;
  const u16t* Vbh = Vt + (size_t)bh * Dd * Tt;
  u16t* Pw = Pl + w * 16 * LDT;

  for (int jt = j0; jt < j1; ++jt) {
    __syncthreads();
    {
      const u16t* ksrc = Kbh + (size_t)jt * 64 * 64;
#pragma unroll
      for (int i = 0; i < 2; ++i) {
        int idx = tid * 2 + i;
        int row = idx >> 3, c8 = idx & 7;
        *(uint4*)&Kl[row * LDT + c8 * 8] = *(const uint4*)(ksrc + row * 64 + c8 * 8);
        *(uint4*)&Vl[row * LDT + c8 * 8] =
            *(const uint4*)(Vbh + (size_t)row * Tt + jt * 64 + c8 * 8);
      }
    }
    __syncthreads();

    float4v S[4];
#pragma unroll
    for (int nc = 0; nc < 4; ++nc) {
      short8 kf0 = *(const short8*)&Kl[(nc * 16 + l15) * LDT + q4 * 8];
      short8 kf1 = *(const short8*)&Kl[(nc * 16 + l15) * LDT + 32 + q4 * 8];
      float4v s = (float4v){0.f, 0.f, 0.f, 0.f};
      s = MFMA16(qf0, kf0, s);
      s = MFMA16(qf1, kf1, s);
      S[nc] = s;
    }

    if (jt == qt) {  // diagonal tile: col > row -> -inf (only in last chunk)
      int rloc = w * 16 + q4 * 4;
#pragma unroll
      for (int nc = 0; nc < 4; ++nc)
#pragma unroll
        for (int reg = 0; reg < 4; ++reg)
          if (nc * 16 + l15 > rloc + reg) S[nc][reg] = -1e30f;
    }

    float alpha[4];
#pragma unroll
    for (int reg = 0; reg < 4; ++reg) {
      float v = fmaxf(fmaxf(S[0][reg], S[1][reg]), fmaxf(S[2][reg], S[3][reg]));
#pragma unroll
      for (int off = 1; off < 16; off <<= 1) v = fmaxf(v, __shfl_xor(v, off));
      float mn = fmaxf(m_[reg], v);
      alpha[reg] = fexp2(m_[reg] - mn);
      m_[reg] = mn;
    }
#pragma unroll
    for (int reg = 0; reg < 4; ++reg) {
      float s = 0.f;
#pragma unroll
      for (int nc = 0; nc < 4; ++nc) {
        float p = fexp2(S[nc][reg] - m_[reg]);
        S[nc][reg] = p;
        s += p;
      }
#pragma unroll
      for (int off = 1; off < 16; off <<= 1) s += __shfl_xor(s, off);
      l_[reg] = l_[reg] * alpha[reg] + s;
    }

#pragma unroll
    for (int nc = 0; nc < 4; ++nc)
#pragma unroll
      for (int reg = 0; reg < 4; ++reg)
        Pw[(q4 * 4 + reg) * LDT + nc * 16 + l15] = f2bf_trunc(S[nc][reg]);
#pragma unroll
    for (int nc = 0; nc < 4; ++nc)
#pragma unroll
      for (int reg = 0; reg < 4; ++reg) O[nc][reg] *= alpha[reg];
    // (no barrier: Pw is wave-private)

    short8 pf0 = *(const short8*)&Pw[l15 * LDT + q4 * 8];
    short8 pf1 = *(const short8*)&Pw[l15 * LDT + 32 + q4 * 8];
#pragma unroll
    for (int nc = 0; nc < 4; ++nc) {
      short8 vf0 = *(const short8*)&Vl[(nc * 16 + l15) * LDT + q4 * 8];
      short8 vf1 = *(const short8*)&Vl[(nc * 16 + l15) * LDT + 32 + q4 * 8];
      O[nc] = MFMA16(pf0, vf0, O[nc]);
      O[nc] = MFMA16(pf1, vf1, O[nc]);
    }
  }

  if (qt < 16) {  // single-chunk: final result
#pragma unroll
    for (int reg = 0; reg < 4; ++reg) {
      float inv = 1.0f / l_[reg];
      int t = qt * 64 + w * 16 + q4 * 4 + reg;
      size_t obase = ((size_t)b * Tt + t) * (Hh * Dd) + h * Dd;
#pragma unroll
      for (int nc = 0; nc < 4; ++nc)
        att[obase + nc * 16 + l15] = f2bf(O[nc][reg] * inv);
    }
  } else {  // write f32 partial (O, m, l) for merge
    float* ps = pbuf + (size_t)(bh * 32 + (qt - 16) * 2 + jc) * PSLOT;
#pragma unroll
    for (int reg = 0; reg < 4; ++reg) {
      int row = w * 16 + q4 * 4 + reg;
#pragma unroll
      for (int nc = 0; nc < 4; ++nc)
        ps[row * 64 + nc * 16 + l15] = O[nc][reg];
      if (l15 == 0) {
        ps[4096 + row] = m_[reg];
        ps[4096 + 64 + row] = l_[reg];
      }
    }
  }
}

// ---------------------------------------------------------------------------
// Kernel 2b: merge the 2 j-chunk partials for each (bh, qt>=16).
// Grid: 24*16 = 384 blocks, 256 thr; thread = (row, 16-col group).
// ---------------------------------------------------------------------------
__global__ __launch_bounds__(256) void merge_kernel(
    const float* __restrict__ pbuf, u16t* __restrict__ att) {
  int bid = blockIdx.x;
  int bh = bid >> 4, qtl = bid & 15;
  int b = bh / Hh, h = bh - b * Hh;
  int tid = threadIdx.x;
  int row = tid >> 2, cg = (tid & 3) * 16;

  const float* p0 = pbuf + (size_t)(bh * 32 + qtl * 2) * PSLOT;
  const float* p1 = p0 + PSLOT;
  float m0 = p0[4096 + row], l0 = p0[4096 + 64 + row];
  float m1 = p1[4096 + row], l1 = p1[4096 + 64 + row];
  float M = fmaxf(m0, m1);
  float w0 = fexp2(m0 - M), w1 = fexp2(m1 - M);
  float inv = 1.0f / (w0 * l0 + w1 * l1);

  short8 o0, o1;
#pragma unroll
  for (int i = 0; i < 8; ++i) {
    o0[i] = (short)f2bf((w0 * p0[row * 64 + cg + i] + w1 * p1[row * 64 + cg + i]) * inv);
    o1[i] = (short)f2bf((w0 * p0[row * 64 + cg + 8 + i] + w1 * p1[row * 64 + cg + 8 + i]) * inv);
  }
  int t = (16 + qtl) * 64 + row;
  u16t* dst = att + ((size_t)b * Tt + t) * (Hh * Dd) + h * Dd + cg;
  *(short8*)dst = o0;
  *(short8*)(dst + 8) = o1;
}

// ---------------------------------------------------------------------------
// Kernel 3: out = att[8192, 384] @ W_proj[384, 64] + b_proj, via MFMA.
// ---------------------------------------------------------------------------
constexpr int LDP = 392;  // 384+8

__global__ __launch_bounds__(256) void proj_kernel(
    const u16t* __restrict__ att, const float* __restrict__ Wp,
    const float* __restrict__ bp, float* __restrict__ out) {
  __shared__ __align__(16) u16t wpt[64 * LDP];  // 50176 B

  int bid = blockIdx.x;
  int tid = threadIdx.x;
  int w = tid >> 6, lane = tid & 63;
  int l15 = lane & 15, q4 = lane >> 4;

#pragma unroll 8
  for (int i = 0; i < 96; ++i) {
    int idx = tid + i * 256;
    int r = idx >> 6, c = idx & 63;
    wpt[c * LDP + r] = f2bf(Wp[idx]);
  }
  __syncthreads();

  int row0 = bid * 64 + w * 16;
  const u16t* arow = att + (size_t)(row0 + l15) * 384;

  float4v acc[4];
#pragma unroll
  for (int nc = 0; nc < 4; ++nc) acc[nc] = (float4v){0.f, 0.f, 0.f, 0.f};

#pragma unroll
  for (int kc = 0; kc < 12; ++kc) {
    short8 a = *(const short8*)(arow + kc * 32 + q4 * 8);
#pragma unroll
    for (int nc = 0; nc < 4; ++nc) {
      short8 bfr = *(const short8*)&wpt[(nc * 16 + l15) * LDP + kc * 32 + q4 * 8];
      acc[nc] = MFMA16(a, bfr, acc[nc]);
    }
  }

  float bv[4];
#pragma unroll
  for (int nc = 0; nc < 4; ++nc) bv[nc] = bp[nc * 16 + l15];
#pragma unroll
  for (int reg = 0; reg < 4; ++reg) {
    int t = row0 + q4 * 4 + reg;
    size_t obase = (size_t)t * 64;
#pragma unroll
    for (int nc = 0; nc < 4; ++nc)
      out[obase + nc * 16 + l15] = acc[nc][reg] + bv[nc];
  }
}

// ---------------------------------------------------------------------------
extern "C" void kernel_launch(void* const* d_in, const int* in_sizes, int n_in,
                              void* d_out, int out_size, void* d_ws, size_t ws_size,
                              hipStream_t stream) {
  const float* x  = (const float*)d_in[0];
  const float* y  = (const float*)d_in[1];
  const float* Wq = (const float*)d_in[2];
  const float* Wk = (const float*)d_in[3];
  const float* Wv = (const float*)d_in[4];
  const float* Wp = (const float*)d_in[5];
  const float* bp = (const float*)d_in[6];
  float* out = (float*)d_out;

  const size_t NBH = (size_t)BH * Tt * Dd;  // 3,145,728 elems
  u16t* Qs   = (u16t*)d_ws;
  u16t* Ks   = Qs + NBH;
  u16t* Vts  = Ks + NBH;
  u16t* attb = Vts + NBH;                     // [B,T,H*D], 3,145,728 elems
  float* pbuf = (float*)(attb + NBH);         // 768 slots * 4224 f32 = 13 MB

  qkv_kernel<<<BH * NQT, 256, 0, stream>>>(x, y, Wq, Wk, Wv, Qs, Ks, Vts);
  attn_kernel<<<BH * RPB, 256, 0, stream>>>(Qs, Ks, Vts, attb, pbuf);
  merge_kernel<<<BH * 16, 256, 0, stream>>>(pbuf, attb);
  proj_kernel<<<(Bb * Tt) / 64, 256, 0, stream>>>(attb, Wp, bp, out);
}

// Round 7
// 122.487 us; speedup vs baseline: 1.3091x; 1.3091x over previous
//
#include <hip/hip_runtime.h>

// Problem dims (fixed): B=4, T=2048, C=64, H=6, D=64, scale = 1/8.
// I/O dtype: float32 (bf16-rounded values). Internal Q/K/Vt/att are bf16.
// Round-7: attn rebuilt on NO-MAX linear softmax (exp2 domain; f32 range makes
// max-subtraction unnecessary: |S*log2e/8| << 120) + BK=128 (2 k-tiles per
// barrier pair). Split-j/merge removed. qkv: 3 barriers (was 7), float4
// weight staging, weight-LDS reused as store bounce. proj: float4 staging.

typedef unsigned short u16t;
typedef __attribute__((ext_vector_type(8))) short short8;   // 8 bf16 (MFMA A/B frag)
typedef __attribute__((ext_vector_type(4))) float float4v;  // MFMA C/D frag

#define MFMA16(a, b, c) __builtin_amdgcn_mfma_f32_16x16x32_bf16((a), (b), (c), 0, 0, 0)

__device__ __forceinline__ float fexp2(float x) {  // v_exp_f32: D = 2^S0
  return __builtin_amdgcn_exp2f(x);
}
__device__ __forceinline__ float bf2f(u16t u) {
  return __uint_as_float(((unsigned)u) << 16);
}
__device__ __forceinline__ u16t f2bf(float f) {  // round-nearest-even
  unsigned u = __float_as_uint(f);
  u += 0x7fffu + ((u >> 16) & 1u);
  return (u16t)(u >> 16);
}
__device__ __forceinline__ u16t f2bf_trunc(float f) {  // truncate (P only)
  return (u16t)(__float_as_uint(f) >> 16);
}
__device__ __forceinline__ short8 load8_f32_bf16(const float* p) {
  float4 f0 = *(const float4*)p;
  float4 f1 = *(const float4*)(p + 4);
  short8 r;
  r[0] = (short)f2bf(f0.x); r[1] = (short)f2bf(f0.y);
  r[2] = (short)f2bf(f0.z); r[3] = (short)f2bf(f0.w);
  r[4] = (short)f2bf(f1.x); r[5] = (short)f2bf(f1.y);
  r[6] = (short)f2bf(f1.z); r[7] = (short)f2bf(f1.w);
  return r;
}

constexpr int Bb = 4, Tt = 2048, Cc = 64, Hh = 6, Dd = 64;
constexpr int BH = Bb * Hh;         // 24
constexpr int NQT = Tt / 64;        // 32 q-tiles of 64 rows
constexpr int LDT = 72;             // 64-col LDS row stride (144 B)
constexpr int LDV = 136;            // 128-col LDS row stride (272 B)
// exp2-domain: S' = S*log2(e); folded into Q pre-scale. No max subtraction
// (f32 exponent range covers |S'| < 120; actual |S'| ~< 15).
#define QSCALE (0.125f * 1.44269504088896f)

// ---------------------------------------------------------------------------
// Kernel 1: QKV projection via MFMA. Per block: one (b,h), 64 t-rows.
// float4 weight loads -> transposed bf16 LDS (B-operand layout). After MFMA,
// the SAME weight LDS buffers are reused as bounce buffers for coalesced
// b128 global stores of Q / K / Vt. 3 barriers total.
// Grid: BH * 32 = 768, 256 thr (4 waves x 16 rows).
// ---------------------------------------------------------------------------
__global__ __launch_bounds__(256) void qkv_kernel(
    const float* __restrict__ x, const float* __restrict__ y,
    const float* __restrict__ Wq, const float* __restrict__ Wk,
    const float* __restrict__ Wv,
    u16t* __restrict__ Q, u16t* __restrict__ K, u16t* __restrict__ Vt) {
  __shared__ __align__(16) u16t wtq[64 * LDT];
  __shared__ __align__(16) u16t wtk[64 * LDT];
  __shared__ __align__(16) u16t wtv[64 * LDT];

  int bid = blockIdx.x;
  int bh = bid >> 5, tt = bid & 31;
  int b = bh / Hh, h = bh - b * Hh;
  int tid = threadIdx.x;
  int w = tid >> 6, lane = tid & 63;
  int l15 = lane & 15, q4 = lane >> 4;

  // Stage weights transposed: wt[d][c] = W[c][d], bf16 (float4 global reads).
  {
    const float4* wq4 = (const float4*)(Wq + h * 4096);
    const float4* wk4 = (const float4*)(Wk + h * 4096);
    const float4* wv4 = (const float4*)(Wv + h * 4096);
#pragma unroll
    for (int i = 0; i < 4; ++i) {
      int fidx = tid + i * 256;     // 0..1023 float4 chunks, coalesced
      float4 qv = wq4[fidx], kv = wk4[fidx], vv = wv4[fidx];
      int base = fidx * 4;
      int c = base >> 6, d0 = base & 63;  // 4 consecutive d, same c
      wtq[(d0 + 0) * LDT + c] = f2bf(qv.x);
      wtq[(d0 + 1) * LDT + c] = f2bf(qv.y);
      wtq[(d0 + 2) * LDT + c] = f2bf(qv.z);
      wtq[(d0 + 3) * LDT + c] = f2bf(qv.w);
      wtk[(d0 + 0) * LDT + c] = f2bf(kv.x);
      wtk[(d0 + 1) * LDT + c] = f2bf(kv.y);
      wtk[(d0 + 2) * LDT + c] = f2bf(kv.z);
      wtk[(d0 + 3) * LDT + c] = f2bf(kv.w);
      wtv[(d0 + 0) * LDT + c] = f2bf(vv.x);
      wtv[(d0 + 1) * LDT + c] = f2bf(vv.y);
      wtv[(d0 + 2) * LDT + c] = f2bf(vv.z);
      wtv[(d0 + 3) * LDT + c] = f2bf(vv.w);
    }
  }

  int trow = tt * 64 + w * 16 + l15;
  const float* xrow = x + ((size_t)b * Tt + trow) * Cc;
  const float* yrow = y + ((size_t)b * Tt + trow) * Cc;
  short8 xa[2], ya[2];
#pragma unroll
  for (int kc = 0; kc < 2; ++kc) {
    xa[kc] = load8_f32_bf16(xrow + kc * 32 + q4 * 8);
    ya[kc] = load8_f32_bf16(yrow + kc * 32 + q4 * 8);
  }
  __syncthreads();  // barrier 1: weights staged

  float4v qa4[4], ka4[4], va4[4];
#pragma unroll
  for (int nc = 0; nc < 4; ++nc) {
    qa4[nc] = (float4v){0.f, 0.f, 0.f, 0.f};
    ka4[nc] = (float4v){0.f, 0.f, 0.f, 0.f};
    va4[nc] = (float4v){0.f, 0.f, 0.f, 0.f};
  }
#pragma unroll
  for (int nc = 0; nc < 4; ++nc) {
#pragma unroll
    for (int kc = 0; kc < 2; ++kc) {
      int off = (nc * 16 + l15) * LDT + kc * 32 + q4 * 8;
      short8 bq = *(const short8*)&wtq[off];
      short8 bk = *(const short8*)&wtk[off];
      short8 bv = *(const short8*)&wtv[off];
      qa4[nc] = MFMA16(xa[kc], bq, qa4[nc]);
      ka4[nc] = MFMA16(ya[kc], bk, ka4[nc]);
      va4[nc] = MFMA16(ya[kc], bv, va4[nc]);
    }
  }
  __syncthreads();  // barrier 2: all waves done READING weights; reuse as bounce

  // Scatter results (C-layout) into the three LDS buffers.
#pragma unroll
  for (int reg = 0; reg < 4; ++reg) {
    int rloc = w * 16 + q4 * 4 + reg;
#pragma unroll
    for (int nc = 0; nc < 4; ++nc) {
      wtq[rloc * LDT + nc * 16 + l15] = f2bf(qa4[nc][reg] * QSCALE);  // exp2-domain
      wtk[rloc * LDT + nc * 16 + l15] = f2bf(ka4[nc][reg]);
      wtv[(nc * 16 + l15) * LDT + rloc] = f2bf(va4[nc][reg]);  // transposed V
    }
  }
  __syncthreads();  // barrier 3: bounce complete

  size_t tilebase = ((size_t)bh * Tt + tt * 64) * Dd;
#pragma unroll
  for (int i = 0; i < 2; ++i) {
    int id = tid * 2 + i;  // 0..511 chunks of 8 bf16
    int row = id >> 3, c8 = id & 7;
    *(uint4*)&Q[tilebase + row * 64 + c8 * 8] = *(const uint4*)&wtq[row * LDT + c8 * 8];
    *(uint4*)&K[tilebase + row * 64 + c8 * 8] = *(const uint4*)&wtk[row * LDT + c8 * 8];
    *(uint4*)&Vt[((size_t)bh * 64 + row) * Tt + tt * 64 + c8 * 8] =
        *(const uint4*)&wtv[row * LDT + c8 * 8];
  }
}

// ---------------------------------------------------------------------------
// Kernel 2: causal flash attention, BK=128, no-max linear softmax.
// Block = (bh, qt): 64 q-rows, 4 waves x 16 rows. Each iteration stages a
// 128-col K/V slab (2 barriers) and does 32 MFMAs/wave. P = exp2(S') with no
// max subtraction; row-sum l accumulates per-lane, reduced once at the end.
// Grid: 768 blocks (qt descending). LDS 53.25 KB -> 3 blocks/CU.
// ---------------------------------------------------------------------------
__global__ __launch_bounds__(256) void attn_kernel(
    const u16t* __restrict__ Q, const u16t* __restrict__ K,
    const u16t* __restrict__ Vt, u16t* __restrict__ att) {
  __shared__ __align__(16) u16t Kl[128 * LDT];     // [j 0..127][c 0..63]
  __shared__ __align__(16) u16t Vl[64 * LDV];      // [d 0..63][j 0..127]
  __shared__ __align__(16) u16t Pl[4 * 16 * LDV];  // per-wave [16][128]

  int bid = blockIdx.x;
  int bh = bid % BH;
  int qt = (NQT - 1) - bid / BH;  // big tiles first
  int b = bh / Hh, h = bh - (bh / Hh) * Hh;
  int tid = threadIdx.x;
  int w = tid >> 6;
  int lane = tid & 63;
  int l15 = lane & 15, q4 = lane >> 4;

  const u16t* Qbase = Q + ((size_t)bh * Tt + qt * 64 + w * 16 + l15) * Dd;
  short8 qf0 = *(const short8*)(Qbase + q4 * 8);
  short8 qf1 = *(const short8*)(Qbase + 32 + q4 * 8);

  float4v O[4];
#pragma unroll
  for (int nc = 0; nc < 4; ++nc) O[nc] = (float4v){0.f, 0.f, 0.f, 0.f};
  float l_[4] = {0.f, 0.f, 0.f, 0.f};  // per-lane partial row sums

  const u16t* Kbh = K + (size_t)bh * Tt * Dd;
  const u16t* Vbh = Vt + (size_t)bh * Dd * Tt;
  u16t* Pw = Pl + w * 16 * LDV;
  const int jmax = qt >> 1;  // 128-col slabs; slab jmax holds the diagonal

  for (int jt = 0; jt <= jmax; ++jt) {
    __syncthreads();  // previous iteration's LDS reads done
    {
      const u16t* ksrc = Kbh + (size_t)jt * 128 * 64;  // contiguous 16KB
      const u16t* vsrc = Vbh + jt * 128;
#pragma unroll
      for (int i = 0; i < 4; ++i) {
        int ci = tid + i * 256;  // 0..1023 chunks of 8 bf16
        int kr = ci >> 3, kc8 = ci & 7;
        *(uint4*)&Kl[kr * LDT + kc8 * 8] = *(const uint4*)(ksrc + kr * 64 + kc8 * 8);
        int vd = ci >> 4, vj8 = ci & 15;
        *(uint4*)&Vl[vd * LDV + vj8 * 8] = *(const uint4*)(vsrc + (size_t)vd * Tt + vj8 * 8);
      }
    }
    __syncthreads();

    // S = Q K^T over 8 col-groups (16 MFMAs/wave)
    float4v S[8];
#pragma unroll
    for (int nc = 0; nc < 8; ++nc) {
      short8 kf0 = *(const short8*)&Kl[(nc * 16 + l15) * LDT + q4 * 8];
      short8 kf1 = *(const short8*)&Kl[(nc * 16 + l15) * LDT + 32 + q4 * 8];
      float4v s = (float4v){0.f, 0.f, 0.f, 0.f};
      s = MFMA16(qf0, kf0, s);
      s = MFMA16(qf1, kf1, s);
      S[nc] = s;
    }

    if (jt == jmax) {  // diagonal slab: col > row -> -inf
      int rloc = qt * 64 + w * 16 + q4 * 4;
      int cbase = jt * 128 + l15;
#pragma unroll
      for (int nc = 0; nc < 8; ++nc)
#pragma unroll
        for (int reg = 0; reg < 4; ++reg)
          if (cbase + nc * 16 > rloc + reg) S[nc][reg] = -1e30f;
    }

    // P = exp2(S) (no max; shift-invariance + f32 range). Accumulate l,
    // write P to LDS (C-layout -> A-layout round trip).
#pragma unroll
    for (int nc = 0; nc < 8; ++nc) {
#pragma unroll
      for (int reg = 0; reg < 4; ++reg) {
        float p = fexp2(S[nc][reg]);
        l_[reg] += p;
        Pw[(q4 * 4 + reg) * LDV + nc * 16 + l15] = f2bf_trunc(p);
      }
    }
    // (no barrier: Pw is wave-private; lgkmcnt orders write->read)

    short8 pf[4];
#pragma unroll
    for (int kc2 = 0; kc2 < 4; ++kc2)
      pf[kc2] = *(const short8*)&Pw[l15 * LDV + kc2 * 32 + q4 * 8];
#pragma unroll
    for (int nc = 0; nc < 4; ++nc) {
#pragma unroll
      for (int kc2 = 0; kc2 < 4; ++kc2) {
        short8 vf = *(const short8*)&Vl[(nc * 16 + l15) * LDV + kc2 * 32 + q4 * 8];
        O[nc] = MFMA16(pf[kc2], vf, O[nc]);
      }
    }
  }

  // Epilogue: one 16-lane sum reduce per row, normalize, write.
#pragma unroll
  for (int reg = 0; reg < 4; ++reg) {
    float s = l_[reg];
#pragma unroll
    for (int off = 1; off < 16; off <<= 1) s += __shfl_xor(s, off);
    float inv = 1.0f / s;
    int t = qt * 64 + w * 16 + q4 * 4 + reg;
    size_t obase = ((size_t)b * Tt + t) * (Hh * Dd) + h * Dd;
#pragma unroll
    for (int nc = 0; nc < 4; ++nc)
      att[obase + nc * 16 + l15] = f2bf(O[nc][reg] * inv);
  }
}

// ---------------------------------------------------------------------------
// Kernel 3: out = att[8192, 384] @ W_proj[384, 64] + b_proj, via MFMA.
// float4 Wp staging. Grid: 128 blocks, 4 waves x 16 rows.
// ---------------------------------------------------------------------------
constexpr int LDP = 392;  // 384+8

__global__ __launch_bounds__(256) void proj_kernel(
    const u16t* __restrict__ att, const float* __restrict__ Wp,
    const float* __restrict__ bp, float* __restrict__ out) {
  __shared__ __align__(16) u16t wpt[64 * LDP];  // 50176 B

  int bid = blockIdx.x;
  int tid = threadIdx.x;
  int w = tid >> 6, lane = tid & 63;
  int l15 = lane & 15, q4 = lane >> 4;

  // Stage Wp transposed: wpt[c][i] = Wp[i][c], bf16 (float4 reads).
  const float4* wp4 = (const float4*)Wp;
#pragma unroll
  for (int i = 0; i < 24; ++i) {
    int fidx = tid + i * 256;  // 0..6143
    float4 v = wp4[fidx];
    int base = fidx * 4;
    int r = base >> 6, c0 = base & 63;
    wpt[(c0 + 0) * LDP + r] = f2bf(v.x);
    wpt[(c0 + 1) * LDP + r] = f2bf(v.y);
    wpt[(c0 + 2) * LDP + r] = f2bf(v.z);
    wpt[(c0 + 3) * LDP + r] = f2bf(v.w);
  }
  __syncthreads();

  int row0 = bid * 64 + w * 16;
  const u16t* arow = att + (size_t)(row0 + l15) * 384;

  float4v acc[4];
#pragma unroll
  for (int nc = 0; nc < 4; ++nc) acc[nc] = (float4v){0.f, 0.f, 0.f, 0.f};

#pragma unroll
  for (int kc = 0; kc < 12; ++kc) {
    short8 a = *(const short8*)(arow + kc * 32 + q4 * 8);
#pragma unroll
    for (int nc = 0; nc < 4; ++nc) {
      short8 bfr = *(const short8*)&wpt[(nc * 16 + l15) * LDP + kc * 32 + q4 * 8];
      acc[nc] = MFMA16(a, bfr, acc[nc]);
    }
  }

  float bv[4];
#pragma unroll
  for (int nc = 0; nc < 4; ++nc) bv[nc] = bp[nc * 16 + l15];
#pragma unroll
  for (int reg = 0; reg < 4; ++reg) {
    int t = row0 + q4 * 4 + reg;
    size_t obase = (size_t)t * 64;
#pragma unroll
    for (int nc = 0; nc < 4; ++nc)
      out[obase + nc * 16 + l15] = acc[nc][reg] + bv[nc];
  }
}

// ---------------------------------------------------------------------------
extern "C" void kernel_launch(void* const* d_in, const int* in_sizes, int n_in,
                              void* d_out, int out_size, void* d_ws, size_t ws_size,
                              hipStream_t stream) {
  const float* x  = (const float*)d_in[0];
  const float* y  = (const float*)d_in[1];
  const float* Wq = (const float*)d_in[2];
  const float* Wk = (const float*)d_in[3];
  const float* Wv = (const float*)d_in[4];
  const float* Wp = (const float*)d_in[5];
  const float* bp = (const float*)d_in[6];
  float* out = (float*)d_out;

  const size_t NBH = (size_t)BH * Tt * Dd;  // 3,145,728 elems
  u16t* Qs   = (u16t*)d_ws;
  u16t* Ks   = Qs + NBH;
  u16t* Vts  = Ks + NBH;
  u16t* attb = Vts + NBH;  // [B,T,H*D] internal bf16

  qkv_kernel<<<BH * NQT, 256, 0, stream>>>(x, y, Wq, Wk, Wv, Qs, Ks, Vts);
  attn_kernel<<<BH * NQT, 256, 0, stream>>>(Qs, Ks, Vts, attb);
  proj_kernel<<<(Bb * Tt) / 64, 256, 0, stream>>>(attb, Wp, bp, out);
}